// Round 6
// baseline (344.855 us; speedup 1.0000x reference)
//
#include <hip/hip_runtime.h>

// Problem constants
#define NN     65536      // H*W (H=W=256)
#define NBLK2  128        // blocks per batch; each handles 512 pixels (2 tiles of 256)

typedef short bf16x8 __attribute__((ext_vector_type(8)));
typedef float f32x4v __attribute__((ext_vector_type(4)));
typedef unsigned short ushort_t;
typedef unsigned int uint_t;

// ---- main_kernel LDS layout (bytes) ----
#define XSTR   72                 // xs row stride in bf16 units (144 B, 16B-aligned)
#define XHI_B  0                  // bf16 [256][72]  = 36864 B
#define XLO_B  36864              // bf16 [256][72]  (aliased by lga after phase A)
#define LGA_B  36864              // f32  [256][28]  = 28672 B
#define LGSTR  28
#define RED_B  73728              // f32 red[128]
#define SMEM_BYTES 74240          // 2 blocks/CU

// ---- workspace byte offsets ----
#define WTHI_B  0                 // bf16 [8][32][64] (coeff-major, rows 24..31 zero)
#define WTLO_B  32768
#define CJ_B    65536             // f32 [8][24]
#define PM_B    66304             // f32 [8*128*8] = 32768 B
#define PL_B    99072
#define PSP_B   131840            // f32 [..][2]
#define PSX_B   197376            // f32 [..][64] = 2 MB
#define Q_B     2294528           // f32 [8][8][4][68]
#define QSTR    68

// ---------- helpers ----------
__device__ __forceinline__ uint_t bf16_rne_bits(float f) {
  uint_t u = __float_as_uint(f);
  return (u + 0x7FFFu + ((u >> 16) & 1u)) >> 16;
}
__device__ __forceinline__ uint_t pack2_bf16(float f0, float f1) {
#if __has_builtin(__builtin_amdgcn_cvt_pk_bf16_f32)
  auto r = __builtin_amdgcn_cvt_pk_bf16_f32(f0, f1);
  if constexpr (sizeof(r) == 4) {
    uint_t u; __builtin_memcpy(&u, &r, 4);
    return u;
  } else {
    return bf16_rne_bits(f0) | (bf16_rne_bits(f1) << 16);
  }
#else
  return bf16_rne_bits(f0) | (bf16_rne_bits(f1) << 16);
#endif
}
template <int CTRL>
__device__ __forceinline__ float dpp_add(float x) {
  int t = __builtin_amdgcn_update_dpp(0, __float_as_int(x), CTRL, 0xf, 0xf, false);
  return x + __int_as_float(t);
}
template <int CTRL>
__device__ __forceinline__ float dpp_maxs(float x) {
  int t = __builtin_amdgcn_update_dpp((int)0xFF800000u, __float_as_int(x), CTRL, 0xf, 0xf, false);
  return fmaxf(x, __int_as_float(t));
}
__device__ __forceinline__ float wave_sum(float x) {
  x = dpp_add<0x111>(x); x = dpp_add<0x112>(x); x = dpp_add<0x114>(x);
  x = dpp_add<0x118>(x); x = dpp_add<0x142>(x); x = dpp_add<0x143>(x);
  return __int_as_float(__builtin_amdgcn_readlane(__float_as_int(x), 63));
}
__device__ __forceinline__ float wave_max(float x) {
  x = dpp_maxs<0x111>(x); x = dpp_maxs<0x112>(x); x = dpp_maxs<0x114>(x);
  x = dpp_maxs<0x118>(x); x = dpp_maxs<0x142>(x); x = dpp_maxs<0x143>(x);
  return __int_as_float(__builtin_amdgcn_readlane(__float_as_int(x), 63));
}

// ---------------- K0: effective weights, split-bf16, B-fragment layout ----------------
__global__ __launch_bounds__(64) void prep_kernel(
    const float* __restrict__ z,  const float* __restrict__ Wq, const float* __restrict__ bq,
    const float* __restrict__ Wk, const float* __restrict__ bk,
    const float* __restrict__ Wp, const float* __restrict__ bp,
    ushort_t* __restrict__ WThi, ushort_t* __restrict__ WTlo, float* __restrict__ Cj)
{
  const int h = blockIdx.x, b = blockIdx.y, t = threadIdx.x;
  __shared__ float q[32];
  if (t < 32) {
    const int e = h*32 + t;
    float a = bq[e];
    const float* zr = z + b*64;
    const float* wr = Wq + e*64;
    #pragma unroll 8
    for (int c = 0; c < 64; ++c) a += zr[c]*wr[c];
    q[t] = a;
  }
  __syncthreads();
  const int c = t;
  float w[3] = {0.f, 0.f, 0.f};
  #pragma unroll 4
  for (int hd = 0; hd < 32; ++hd) {
    const float qk = q[hd] * Wk[(h*32+hd)*64 + c];
    w[0] += qk * bp[hd];
    w[1] += qk * Wp[hd*2+0];
    w[2] += qk * Wp[hd*2+1];
  }
  #pragma unroll
  for (int j = 0; j < 3; ++j) {
    const int coeff = h*3 + j;
    const uint_t hb = bf16_rne_bits(w[j]);
    const float  fh = __uint_as_float(hb << 16);
    const uint_t lb = bf16_rne_bits(w[j] - fh);
    WThi[(b*32 + coeff)*64 + c] = (ushort_t)hb;
    WTlo[(b*32 + coeff)*64 + c] = (ushort_t)lb;
  }
  if (h == 0) {
    #pragma unroll
    for (int r = 0; r < 8; ++r) {
      WThi[(b*32 + 24 + r)*64 + c] = 0;
      WTlo[(b*32 + 24 + r)*64 + c] = 0;
    }
  }
  if (t < 3) {
    float s = 0.f;
    for (int hd = 0; hd < 32; ++hd) {
      const float m = (t == 0) ? bp[hd] : Wp[hd*2 + (t-1)];
      s += q[hd] * m * bk[h*32+hd];
    }
    Cj[b*24 + h*3 + t] = s;
  }
}

// ---------------- K1: 2-tile pipelined MFMA logits + online softmax + weighted-x ----------------
__global__ __launch_bounds__(256, 2) void main_kernel(
    const float* __restrict__ x, const float* __restrict__ pos,
    const ushort_t* __restrict__ WThi, const ushort_t* __restrict__ WTlo,
    const float* __restrict__ Cj,
    float* __restrict__ Pm, float* __restrict__ Pl,
    float* __restrict__ Psp, float* __restrict__ Psx)
{
  extern __shared__ char smc[];
  ushort_t* xhi = (ushort_t*)(smc + XHI_B);
  ushort_t* xlo = (ushort_t*)(smc + XLO_B);
  float*    lga = (float*)(smc + LGA_B);
  float*    red = (float*)(smc + RED_B);
  const int t   = threadIdx.x;
  const int blk = blockIdx.x;       // 0..127
  const int b   = blockIdx.y;
  const int wid = t >> 6, lid = t & 63;
  const int c0  = lid & 15, q4 = lid >> 4;

  // ---- issue tile-0 global loads first (64 b32, coalesced) ----
  float F[64];
  const float* xg = x + (size_t)b*64*NN + (size_t)blk*512 + t;
  #pragma unroll
  for (int c = 0; c < 64; ++c) F[c] = xg[(size_t)c*NN];

  // ---- B-fragments + uniform params (land under the x loads) ----
  bf16x8 bh[2][2], bl[2][2];
  {
    const ushort_t* wtb_h = WThi + b*2048;
    const ushort_t* wtb_l = WTlo + b*2048;
    #pragma unroll
    for (int nt = 0; nt < 2; ++nt)
      #pragma unroll
      for (int ks = 0; ks < 2; ++ks) {
        const int off = (nt*16 + c0)*64 + ks*32 + q4*8;
        bh[nt][ks] = *(const bf16x8*)(wtb_h + off);
        bl[nt][ks] = *(const bf16x8*)(wtb_l + off);
      }
  }
  float cj[24];
  {
    const float* cjp = Cj + b*24;
    #pragma unroll
    for (int k = 0; k < 24; ++k) cj[k] = cjp[k];
  }
  float posx[8], py[8];
  #pragma unroll
  for (int h = 0; h < 8; ++h) {
    posx[h] = pos[(b*8+h)*2 + 0];
    py[h]   = pos[(b*8+h)*2 + 1];
  }

  // ---- online-softmax running state (wave-uniform values, per-thread copies) ----
  float Mrun[8], Lrun[8], SJrun[8], SPXrun[8], aB[8];
  #pragma unroll
  for (int h = 0; h < 8; ++h) {
    Mrun[h] = -1e30f; Lrun[h] = 0.f; SJrun[h] = 0.f; SPXrun[h] = 0.f; aB[h] = 0.f;
  }

  const float tf = (float)t;      // gy == n&255 == t for both tiles

  #pragma unroll 1
  for (int tile = 0; tile < 2; ++tile) {
    __syncthreads();   // LDS write-safe (tile1: previous phase-B xhi reads done)

    // ---- convert F -> bf16 hi/lo, store to LDS ----
    #pragma unroll
    for (int cc = 0; cc < 4; ++cc) {
      uint_t H[8], L[8];
      #pragma unroll
      for (int i = 0; i < 8; ++i) {
        const float f0 = F[cc*16 + 2*i], f1 = F[cc*16 + 2*i + 1];
        const uint_t hp = pack2_bf16(f0, f1);
        const float r0 = f0 - __uint_as_float(hp << 16);
        const float r1 = f1 - __uint_as_float(hp & 0xFFFF0000u);
        H[i] = hp;
        L[i] = pack2_bf16(r0, r1);
      }
      char* dh = smc + XHI_B + t*144 + cc*32;
      char* dl = smc + XLO_B + t*144 + cc*32;
      *(uint4*)(dh)      = make_uint4(H[0],H[1],H[2],H[3]);
      *(uint4*)(dh + 16) = make_uint4(H[4],H[5],H[6],H[7]);
      *(uint4*)(dl)      = make_uint4(L[0],L[1],L[2],L[3]);
      *(uint4*)(dl + 16) = make_uint4(L[4],L[5],L[6],L[7]);
    }
    __syncthreads();   // xs ready

    // ---- phase A: D[pixel, coeff] = X(hi+lo) . W^T(hi+lo), 3-term split ----
    f32x4v acc[4][2];
    #pragma unroll
    for (int mt = 0; mt < 4; ++mt) { acc[mt][0] = (f32x4v)0.f; acc[mt][1] = (f32x4v)0.f; }
    {
      const int mrow0 = wid*64;
      #pragma unroll
      for (int mt = 0; mt < 4; ++mt) {
        const int row = mrow0 + mt*16 + c0;
        const ushort_t* ph = xhi + row*XSTR + q4*8;
        const ushort_t* pl = xlo + row*XSTR + q4*8;
        bf16x8 ah0 = *(const bf16x8*)(ph);
        bf16x8 ah1 = *(const bf16x8*)(ph + 32);
        bf16x8 al0 = *(const bf16x8*)(pl);
        bf16x8 al1 = *(const bf16x8*)(pl + 32);
        #pragma unroll
        for (int nt = 0; nt < 2; ++nt) {
          f32x4v a = acc[mt][nt];
          a = __builtin_amdgcn_mfma_f32_16x16x32_bf16(ah0, bh[nt][0], a, 0, 0, 0);
          a = __builtin_amdgcn_mfma_f32_16x16x32_bf16(ah1, bh[nt][1], a, 0, 0, 0);
          a = __builtin_amdgcn_mfma_f32_16x16x32_bf16(ah0, bl[nt][0], a, 0, 0, 0);
          a = __builtin_amdgcn_mfma_f32_16x16x32_bf16(ah1, bl[nt][1], a, 0, 0, 0);
          a = __builtin_amdgcn_mfma_f32_16x16x32_bf16(al0, bh[nt][0], a, 0, 0, 0);
          a = __builtin_amdgcn_mfma_f32_16x16x32_bf16(al1, bh[nt][1], a, 0, 0, 0);
          acc[mt][nt] = a;
        }
      }
    }
    __syncthreads();   // xlo reads done -> lga alias safe

    {
      const int mrow0 = wid*64;
      #pragma unroll
      for (int mt = 0; mt < 4; ++mt)
        #pragma unroll
        for (int r = 0; r < 4; ++r) {
          const int prow = mrow0 + mt*16 + q4*4 + r;
          lga[prow*LGSTR + c0] = acc[mt][0][r];
          if (c0 < 8) lga[prow*LGSTR + 16 + c0] = acc[mt][1][r];
        }
    }
    __syncthreads();   // lga ready

    // ---- per-pixel logits ----
    float a24[24];
    {
      const float4* ap = (const float4*)(lga + t*LGSTR);
      #pragma unroll
      for (int r = 0; r < 6; ++r) *(float4*)(a24 + 4*r) = ap[r];
    }
    const float gxf = (float)(2*blk + tile);   // n>>8
    float lg[8];
    #pragma unroll
    for (int h = 0; h < 8; ++h) {
      const float a0 = a24[h*3+0] + cj[h*3+0];
      const float a1 = a24[h*3+1] + cj[h*3+1];
      const float a2 = a24[h*3+2] + cj[h*3+2];
      lg[h] = (a0 + (gxf - posx[h])*a1 + (tf - py[h])*a2) * 0.17677669529663687f;
    }

    // ---- tile max per head ----
    #pragma unroll
    for (int h = 0; h < 8; ++h) {
      const float m = wave_max(lg[h]);
      if (lid == 0) red[h*4 + wid] = m;
    }
    __syncthreads();

    // ---- online merge: new max, alpha, p ----
    float p[8], alpha[8];
    #pragma unroll
    for (int h = 0; h < 8; ++h) {
      const float Mt = fmaxf(fmaxf(red[h*4+0], red[h*4+1]), fmaxf(red[h*4+2], red[h*4+3]));
      const float Mn = fmaxf(Mrun[h], Mt);
      alpha[h] = __expf(Mrun[h] - Mn);   // tile0: exp(-huge) = 0
      Mrun[h]  = Mn;
      p[h]     = __expf(lg[h] - Mn);
      aB[h]   *= alpha[h];
    }
    #pragma unroll
    for (int h = 0; h < 8; ++h) {
      const float sp  = wave_sum(p[h]);
      const float spj = wave_sum(p[h] * tf);
      if (lid == 0) { red[32 + h*4 + wid] = sp; red[64 + h*4 + wid] = spj; }
    }
    __syncthreads();

    #pragma unroll
    for (int h = 0; h < 8; ++h) {
      const float Lt  = red[32+h*4+0] + red[32+h*4+1] + red[32+h*4+2] + red[32+h*4+3];
      const float SJt = red[64+h*4+0] + red[64+h*4+1] + red[64+h*4+2] + red[64+h*4+3];
      Lrun[h]   = Lrun[h]*alpha[h]   + Lt;
      SJrun[h]  = SJrun[h]*alpha[h]  + SJt;
      SPXrun[h] = SPXrun[h]*alpha[h] + gxf*Lt;
    }

    // ---- prefetch tile-1 x while phase B runs ----
    if (tile == 0) {
      const float* xg1 = xg + 256;
      #pragma unroll
      for (int c = 0; c < 64; ++c) F[c] = xg1[(size_t)c*NN];
    }

    // ---- phase B: aB[h][c=lid] += sum_{j in quarter} p[h][j] * xhi[j][c] ----
    {
      const ushort_t* xrow = xhi + (wid*64)*XSTR + lid;
      #pragma unroll 8
      for (int j = 0; j < 64; ++j) {
        const float xv = __uint_as_float(((uint_t)xrow[j*XSTR]) << 16);
        #pragma unroll
        for (int h = 0; h < 8; ++h) {
          const float pj = __int_as_float(__builtin_amdgcn_readlane(__float_as_int(p[h]), j));
          aB[h] = fmaf(pj, xv, aB[h]);
        }
      }
    }
  }

  // ---- write per-block softmax partials (values uniform across threads) ----
  const int base = (b*NBLK2 + blk)*8;
  if (t == 0) {
    #pragma unroll
    for (int h = 0; h < 8; ++h) {
      Pm[base + h] = Mrun[h];
      Pl[base + h] = Lrun[h];
      Psp[(base + h)*2 + 0] = SPXrun[h];
      Psp[(base + h)*2 + 1] = SJrun[h];
    }
  }

  // ---- combine aB across waves, write Psx ----
  __syncthreads();   // all phase-B xhi reads done
  {
    float* pstage = (float*)smc;         // [4][8][64]
    #pragma unroll
    for (int h = 0; h < 8; ++h) pstage[(wid*8 + h)*64 + lid] = aB[h];
  }
  __syncthreads();
  {
    const float* pstage = (const float*)smc;
    #pragma unroll
    for (int r = 0; r < 2; ++r) {
      const int idx = t + 256*r;          // (h,c) flat
      const float s = pstage[idx] + pstage[512+idx] + pstage[1024+idx] + pstage[1536+idx];
      Psx[(size_t)base*64 + idx] = s;
    }
  }
}

// ---------------- K2a: combine 32 block-partials per (b,h,g) ----------------
__global__ __launch_bounds__(256) void reduce1_kernel(
    const float* __restrict__ Pm, const float* __restrict__ Pl,
    const float* __restrict__ Psp, const float* __restrict__ Psx,
    float* __restrict__ Q)
{
  const int g = blockIdx.x, h = blockIdx.y, b = blockIdx.z, t = threadIdx.x;
  __shared__ float al[32];
  __shared__ float mgs;
  __shared__ float sums[3];
  __shared__ float sxl[256];
  const int base = (b*NBLK2 + g*32)*8 + h;

  float m_t = -1e30f;
  if (t < 32) m_t = Pm[base + t*8];
  if (t < 64) {
    float mm = m_t;
    #pragma unroll
    for (int off = 16; off >= 1; off >>= 1) mm = fmaxf(mm, __shfl_xor(mm, off, 64));
    if (t == 0) mgs = mm;
  }
  __syncthreads();
  const float Mg = mgs;
  if (t < 32) {
    const float a = __expf(m_t - Mg);
    al[t] = a;
    float lt = Pl[base + t*8] * a;
    float sx = Psp[(base + t*8)*2 + 0] * a;
    float sy = Psp[(base + t*8)*2 + 1] * a;
    #pragma unroll
    for (int off = 16; off >= 1; off >>= 1) {
      lt += __shfl_xor(lt, off, 64);
      sx += __shfl_xor(sx, off, 64);
      sy += __shfl_xor(sy, off, 64);
    }
    if (t == 0) { sums[0] = lt; sums[1] = sx; sums[2] = sy; }
  }
  __syncthreads();
  {
    const int c = t & 63, g2 = t >> 6;
    float acc = 0.f;
    #pragma unroll
    for (int i = 0; i < 8; ++i) {
      const int k = g2*8 + i;
      acc += al[k] * Psx[(size_t)(base + k*8)*64 + c];
    }
    sxl[g2*64 + c] = acc;
  }
  __syncthreads();
  float* q = Q + ((b*8 + h)*4 + g)*QSTR;
  if (t < 64) q[4+t] = sxl[t] + sxl[64+t] + sxl[128+t] + sxl[192+t];
  if (t == 0) { q[0] = Mg; q[1] = sums[0]; q[2] = sums[1]; q[3] = sums[2]; }
}

// ---------------- K2b: final combine + value projection ----------------
__global__ __launch_bounds__(64) void reduce2_kernel(
    const float* __restrict__ Q, const float* __restrict__ Wv, const float* __restrict__ bv,
    float* __restrict__ out)
{
  const int h = blockIdx.x, b = blockIdx.y, t = threadIdx.x;
  __shared__ float qm[4], bl[4], l4[4], sx4[4], sy4[4];
  __shared__ float SXs[64];
  const float* qb = Q + ((b*8 + h)*4)*QSTR;

  if (t < 4) qm[t] = qb[t*QSTR + 0];
  __syncthreads();
  float M = fmaxf(fmaxf(qm[0], qm[1]), fmaxf(qm[2], qm[3]));
  if (t < 4) {
    const float be = __expf(qm[t] - M);
    bl[t]  = be;
    l4[t]  = be * qb[t*QSTR + 1];
    sx4[t] = be * qb[t*QSTR + 2];
    sy4[t] = be * qb[t*QSTR + 3];
  }
  __syncthreads();
  const float L = l4[0] + l4[1] + l4[2] + l4[3];
  const float invL = 1.0f / L;
  {
    float s = 0.f;
    #pragma unroll
    for (int g = 0; g < 4; ++g) s += bl[g] * qb[g*QSTR + 4 + t];
    SXs[t] = s * invL;
  }
  __syncthreads();

  #pragma unroll
  for (int r = 0; r < 4; ++r) {
    const int e = t + 64*r;
    float v = bv[e];
    const float* wvr = Wv + e*64;
    #pragma unroll 8
    for (int c = 0; c < 64; ++c) v += wvr[c] * SXs[c];
    out[(b*8 + h)*256 + e] = v;
  }
  if (t == 0) {
    const float SPx = sx4[0] + sx4[1] + sx4[2] + sx4[3];
    const float SPy = sy4[0] + sy4[1] + sy4[2] + sy4[3];
    out[16384 + (b*8 + h)*2 + 0] = SPx * invL;
    out[16384 + (b*8 + h)*2 + 1] = SPy * invL;
  }
}

extern "C" void kernel_launch(void* const* d_in, const int* in_sizes, int n_in,
                              void* d_out, int out_size, void* d_ws, size_t ws_size,
                              hipStream_t stream)
{
  const float* x   = (const float*)d_in[0];
  const float* z   = (const float*)d_in[1];
  const float* pos = (const float*)d_in[2];
  const float* Wq  = (const float*)d_in[3];
  const float* bq  = (const float*)d_in[4];
  const float* Wk  = (const float*)d_in[5];
  const float* bk  = (const float*)d_in[6];
  const float* Wv  = (const float*)d_in[7];
  const float* bv  = (const float*)d_in[8];
  const float* Wp  = (const float*)d_in[9];
  const float* bp  = (const float*)d_in[10];
  float* out = (float*)d_out;
  char*  wsb = (char*)d_ws;

  ushort_t* WThi = (ushort_t*)(wsb + WTHI_B);
  ushort_t* WTlo = (ushort_t*)(wsb + WTLO_B);
  float* Cj  = (float*)(wsb + CJ_B);
  float* Pm  = (float*)(wsb + PM_B);
  float* Pl  = (float*)(wsb + PL_B);
  float* Psp = (float*)(wsb + PSP_B);
  float* Psx = (float*)(wsb + PSX_B);
  float* Q   = (float*)(wsb + Q_B);

  (void)hipFuncSetAttribute((const void*)main_kernel,
                            hipFuncAttributeMaxDynamicSharedMemorySize, SMEM_BYTES);

  prep_kernel   <<<dim3(8,8),     64,  0,          stream>>>(z, Wq, bq, Wk, bk, Wp, bp, WThi, WTlo, Cj);
  main_kernel   <<<dim3(NBLK2,8), 256, SMEM_BYTES, stream>>>(x, pos, WThi, WTlo, Cj, Pm, Pl, Psp, Psx);
  reduce1_kernel<<<dim3(4,8,8),   256, 0,          stream>>>(Pm, Pl, Psp, Psx, Q);
  reduce2_kernel<<<dim3(8,8),     64,  0,          stream>>>(Q, Wv, bv, out);
}